// Round 3
// baseline (492.177 us; speedup 1.0000x reference)
//
#include <hip/hip_runtime.h>
#include <hip/hip_bf16.h>

#define B_    2
#define NSEQ  2048
#define FDIM  1024
#define NH    16
#define HD    64
#define MTOT  (B_*NSEQ)   // 4096

typedef __bf16 bf16_t;
typedef __bf16 bf16x4 __attribute__((ext_vector_type(4)));
typedef __bf16 bf16x8 __attribute__((ext_vector_type(8)));
typedef float  f32x4  __attribute__((ext_vector_type(4)));

#define AS1 __attribute__((address_space(1)))
#define AS3 __attribute__((address_space(3)))

__device__ __forceinline__ void gld_lds16(const bf16_t* g, bf16_t* l) {
  __builtin_amdgcn_global_load_lds((const AS1 void*)g, (AS3 void*)l, 16, 0, 0);
}

// K=16 bf16 MFMA for PV (P^T C-layout reg r == B-operand k-index j).
// NOTE: all device-builtin probing must live inside __HIP_DEVICE_COMPILE__ —
// the host pass has none of these builtins (round-2 compile failure).
__device__ __forceinline__ f32x4 mfma_pv(bf16x4 a, bf16x4 b, f32x4 c) {
#if defined(__HIP_DEVICE_COMPILE__)
#if __has_builtin(__builtin_amdgcn_mfma_f32_16x16x16bf16_1k)
  typedef short s4 __attribute__((ext_vector_type(4)));
  return __builtin_amdgcn_mfma_f32_16x16x16bf16_1k(
      __builtin_bit_cast(s4, a), __builtin_bit_cast(s4, b), c, 0, 0, 0);
#else
  asm("v_mfma_f32_16x16x16_bf16 %0, %1, %2, %0" : "+v"(c) : "v"(a), "v"(b));
  return c;
#endif
#else
  (void)a; (void)b;
  return c;  // host pass: never executed
#endif
}

// ---------------------------------------------------------------------------
// Kernel 1: fp32 -> bf16 casts for x, Wq, Wk, Wv, Wo
// ---------------------------------------------------------------------------
extern "C" __global__ __launch_bounds__(256) void cast_all_k(
    const float* __restrict__ x,  const float* __restrict__ wq,
    const float* __restrict__ wk, const float* __restrict__ wv,
    const float* __restrict__ wo,
    bf16_t* __restrict__ xb,  bf16_t* __restrict__ wqb,
    bf16_t* __restrict__ wkb, bf16_t* __restrict__ wvb,
    bf16_t* __restrict__ wob)
{
  long t = (long)blockIdx.x * blockDim.x + threadIdx.x;
  long i = t * 4;
  const float* src; bf16_t* dst; long off;
  if      (i < 4194304L) { src = x;  dst = xb;  off = i; }
  else if (i < 5242880L) { src = wq; dst = wqb; off = i - 4194304L; }
  else if (i < 6291456L) { src = wk; dst = wkb; off = i - 5242880L; }
  else if (i < 7340032L) { src = wv; dst = wvb; off = i - 6291456L; }
  else                   { src = wo; dst = wob; off = i - 7340032L; }
  float4 v = *(const float4*)(src + off);
  bf16x4 o = { (bf16_t)v.x, (bf16_t)v.y, (bf16_t)v.z, (bf16_t)v.w };
  *(bf16x4*)(dst + off) = o;
}

// ---------------------------------------------------------------------------
// Kernel 2/4: bf16 GEMM out[m][n] = sum_k A[m][k]*W[n][k]
// mode 0: write Q (pre-scaled by 2^-3, exact) [b][h][tok][d]
// mode 1: write K [b][h][tok][d]
// mode 2: write V transposed [b][h][d][tok]
// mode 3: write fp32 out [m][n] + bias[n]
// ---------------------------------------------------------------------------
extern "C" __global__ __launch_bounds__(256) void gemm_bt_k(
    const bf16_t* __restrict__ A,
    const bf16_t* __restrict__ Bq, const bf16_t* __restrict__ Bk,
    const bf16_t* __restrict__ Bv,
    bf16_t* __restrict__ oq, bf16_t* __restrict__ okk,
    bf16_t* __restrict__ ovt, float* __restrict__ oo,
    const float* __restrict__ bias, int mode_base)
{
  __shared__ __align__(16) bf16_t As[128*32];
  __shared__ __align__(16) bf16_t Bs[128*32];
  const int K = FDIM;
  int mode = mode_base + blockIdx.z;
  const bf16_t* Bw = (mode == 0) ? Bq : (mode == 1) ? Bk : (mode == 2) ? Bv : Bq;
  int m0 = blockIdx.y * 128, n0 = blockIdx.x * 128;
  int tid = threadIdx.x, lane = tid & 63, wave = tid >> 6;
  int g = lane >> 4, c = lane & 15;
  int wm = (wave >> 1) * 64, wn = (wave & 1) * 64;
  f32x4 acc[4][4];
  for (int i = 0; i < 4; ++i)
    for (int j = 0; j < 4; ++j)
      acc[i][j] = (f32x4){0.f, 0.f, 0.f, 0.f};

  int srow = lane >> 2;
  int scol = (lane & 3) * 8;

  for (int kt = 0; kt < K / 32; ++kt) {
    int kk = kt * 32;
    for (int cc = 0; cc < 2; ++cc) {
      int chunk = wave * 2 + cc;
      const bf16_t* ag = A  + (long)(m0 + chunk*16 + srow) * K + kk + scol;
      const bf16_t* bg = Bw + (long)(n0 + chunk*16 + srow) * K + kk + scol;
      gld_lds16(ag, As + chunk * 512);
      gld_lds16(bg, Bs + chunk * 512);
    }
    __syncthreads();
    bf16x8 af[4], bfr[4];
    for (int t = 0; t < 4; ++t) {
      af[t]  = *(const bf16x8*)(As + (wm + t*16 + c) * 32 + g * 8);
      bfr[t] = *(const bf16x8*)(Bs + (wn + t*16 + c) * 32 + g * 8);
    }
    for (int mt = 0; mt < 4; ++mt)
      for (int nt = 0; nt < 4; ++nt)
        acc[mt][nt] = __builtin_amdgcn_mfma_f32_16x16x32_bf16(
            af[mt], bfr[nt], acc[mt][nt], 0, 0, 0);
    __syncthreads();
  }

  if (mode < 2) {
    bf16_t* dst = (mode == 0) ? oq : okk;
    float sc = (mode == 0) ? 0.125f : 1.0f;   // fold softmax scale into Q (2^-3, exact)
    for (int mt = 0; mt < 4; ++mt)
      for (int nt = 0; nt < 4; ++nt) {
        int n = n0 + wn + nt*16 + c;
        int h = n >> 6, d = n & 63;
        for (int r = 0; r < 4; ++r) {
          int m = m0 + wm + mt*16 + g*4 + r;
          int b = m >> 11, tok = m & 2047;
          dst[((long)(b*NH + h) * NSEQ + tok) * HD + d] = (bf16_t)(acc[mt][nt][r] * sc);
        }
      }
  } else if (mode == 2) {
    for (int mt = 0; mt < 4; ++mt)
      for (int nt = 0; nt < 4; ++nt) {
        int n = n0 + wn + nt*16 + c;
        int h = n >> 6, d = n & 63;
        int m = m0 + wm + mt*16 + g*4;
        int b = m >> 11, tok = m & 2047;
        bf16x4 pk = { (bf16_t)acc[mt][nt][0], (bf16_t)acc[mt][nt][1],
                      (bf16_t)acc[mt][nt][2], (bf16_t)acc[mt][nt][3] };
        *(bf16x4*)(ovt + ((long)(b*NH + h) * HD + d) * NSEQ + tok) = pk;
      }
  } else {
    for (int mt = 0; mt < 4; ++mt)
      for (int nt = 0; nt < 4; ++nt) {
        int n = n0 + wn + nt*16 + c;
        float bv = bias[n];
        for (int r = 0; r < 4; ++r) {
          int m = m0 + wm + mt*16 + g*4 + r;
          oo[(long)m * FDIM + n] = acc[mt][nt][r] + bv;
        }
      }
  }
}

// ---------------------------------------------------------------------------
// Kernel 3: flash attention, transposed-S formulation.
//   S^T = K·Q^T  (16x16x32 MFMA; softmax axis = C-layout row axis)
//   O^T = V^T·P^T (16x16x16 MFMA; P^T C-layout IS the B-operand layout)
// Block = 4 INDEPENDENT waves, 16 q-rows each; no barriers in main loop;
// LDS only for the epilogue O^T -> O transpose (coalesced stores).
// ---------------------------------------------------------------------------
extern "C" __global__ __launch_bounds__(256) void attn_fused_k(
    const bf16_t* __restrict__ q, const bf16_t* __restrict__ k,
    const bf16_t* __restrict__ vt, bf16_t* __restrict__ attn)
{
  __shared__ __align__(16) bf16_t Ol[4 * 16 * 80];
  int bh = blockIdx.y;
  int tid = threadIdx.x, lane = tid & 63, wave = tid >> 6;
  int g = lane >> 4, c = lane & 15;
  int qw = blockIdx.x * 64 + wave * 16;
  const bf16_t* Q  = q  + (long)bh * NSEQ * HD;
  const bf16_t* Kp = k  + (long)bh * NSEQ * HD;
  const bf16_t* Vt = vt + (long)bh * HD * NSEQ;

  // B-frag of Q^T: B[k=d][n=q], n=c -> q-row qw+c, k=g*8+j -> d
  bf16x8 bQ0 = *(const bf16x8*)(Q + (long)(qw + c) * HD + g * 8);
  bf16x8 bQ1 = *(const bf16x8*)(Q + (long)(qw + c) * HD + 32 + g * 8);

  f32x4 acc[4];  // O^T tiles: row d = dt*16+g*4+r, col q = c
  for (int dt = 0; dt < 4; ++dt) acc[dt] = (f32x4){0.f, 0.f, 0.f, 0.f};
  float mrun = -1e30f, lrun = 0.f;   // softmax state for q = qw + c

  for (int kt = 0; kt < NSEQ / 64; ++kt) {
    int k0 = kt * 64;
    // S^T tile: rows = 64 keys (4 m-tiles), cols = 16 q
    f32x4 St[4];
#pragma unroll
    for (int mt = 0; mt < 4; ++mt) {
      const bf16_t* kp = Kp + (long)(k0 + mt*16 + c) * HD + g * 8;
      bf16x8 aK0 = *(const bf16x8*)(kp);
      bf16x8 aK1 = *(const bf16x8*)(kp + 32);
      f32x4 z = (f32x4){0.f, 0.f, 0.f, 0.f};
      z = __builtin_amdgcn_mfma_f32_16x16x32_bf16(aK0, bQ0, z, 0, 0, 0);
      z = __builtin_amdgcn_mfma_f32_16x16x32_bf16(aK1, bQ1, z, 0, 0, 0);
      St[mt] = z;
    }
    // per-lane partial max over 16 key-values (pairwise tree), then 2 shfls
    f32x4 vm0 = (f32x4){fmaxf(St[0][0], St[1][0]), fmaxf(St[0][1], St[1][1]),
                        fmaxf(St[0][2], St[1][2]), fmaxf(St[0][3], St[1][3])};
    f32x4 vm1 = (f32x4){fmaxf(St[2][0], St[3][0]), fmaxf(St[2][1], St[3][1]),
                        fmaxf(St[2][2], St[3][2]), fmaxf(St[2][3], St[3][3])};
    float pm = fmaxf(fmaxf(fmaxf(vm0[0], vm1[0]), fmaxf(vm0[1], vm1[1])),
                     fmaxf(fmaxf(vm0[2], vm1[2]), fmaxf(vm0[3], vm1[3])));
    pm = fmaxf(pm, __shfl_xor(pm, 16));
    pm = fmaxf(pm, __shfl_xor(pm, 32));
    float mnew = fmaxf(mrun, pm);
    float alpha = __expf(mrun - mnew);
    f32x4 vsum = (f32x4){0.f, 0.f, 0.f, 0.f};
#pragma unroll
    for (int mt = 0; mt < 4; ++mt) {
#pragma unroll
      for (int r = 0; r < 4; ++r) {
        float p = __expf(St[mt][r] - mnew);
        St[mt][r] = p;
        vsum[r] += p;
      }
    }
    float ps = (vsum[0] + vsum[1]) + (vsum[2] + vsum[3]);
    ps += __shfl_xor(ps, 16);
    ps += __shfl_xor(ps, 32);
    lrun = lrun * alpha + ps;
    mrun = mnew;
#pragma unroll
    for (int dt = 0; dt < 4; ++dt) acc[dt] *= alpha;

    // P^T bf16 frags: C-layout reg r == B-operand k-index j for K=16 MFMA
    bf16x4 bP[4];
#pragma unroll
    for (int mt = 0; mt < 4; ++mt)
      bP[mt] = (bf16x4){(bf16_t)St[mt][0], (bf16_t)St[mt][1],
                        (bf16_t)St[mt][2], (bf16_t)St[mt][3]};

    // O^T += V^T · P^T : A-frag of V^T straight from Vt[d][tok]
#pragma unroll
    for (int mt = 0; mt < 4; ++mt) {
      long vb = k0 + mt*16 + g*4;
#pragma unroll
      for (int dt = 0; dt < 4; ++dt) {
        bf16x4 aV = *(const bf16x4*)(Vt + (long)(dt*16 + c) * NSEQ + vb);
        acc[dt] = mfma_pv(aV, bP[mt], acc[dt]);
      }
    }
  }

  // epilogue: O^T -> LDS -> coalesced O stores
  float invl = 1.f / lrun;
  bf16_t* Ow = Ol + wave * (16 * 80);
#pragma unroll
  for (int dt = 0; dt < 4; ++dt)
#pragma unroll
    for (int r = 0; r < 4; ++r)
      Ow[c * 80 + dt*16 + g*4 + r] = (bf16_t)(acc[dt][r] * invl);
  __syncthreads();
  int b = bh >> 4, h = bh & 15;
  int qr = lane >> 2, dseg = (lane & 3) * 16;
  bf16x8 o0 = *(const bf16x8*)(Ow + qr * 80 + dseg);
  bf16x8 o1 = *(const bf16x8*)(Ow + qr * 80 + dseg + 8);
  bf16_t* dst = attn + ((long)(b * NSEQ + qw + qr)) * FDIM + h * HD + dseg;
  *(bf16x8*)(dst)     = o0;
  *(bf16x8*)(dst + 8) = o1;
}

// ---------------------------------------------------------------------------
extern "C" void kernel_launch(void* const* d_in, const int* in_sizes, int n_in,
                              void* d_out, int out_size, void* d_ws, size_t ws_size,
                              hipStream_t stream)
{
  const float* x  = (const float*)d_in[0];
  const float* wq = (const float*)d_in[1];
  const float* wk = (const float*)d_in[2];
  const float* wv = (const float*)d_in[3];
  const float* wo = (const float*)d_in[4];
  const float* bo = (const float*)d_in[5];
  float* out = (float*)d_out;
  char* ws = (char*)d_ws;

  const size_t MB = 1024 * 1024;
  bf16_t* xb    = (bf16_t*)(ws);
  bf16_t* wqb   = (bf16_t*)(ws + 8  * MB);
  bf16_t* wkb   = (bf16_t*)(ws + 10 * MB);
  bf16_t* wvb   = (bf16_t*)(ws + 12 * MB);
  bf16_t* wob   = (bf16_t*)(ws + 14 * MB);
  bf16_t* q_ws  = (bf16_t*)(ws + 16 * MB);
  bf16_t* k_ws  = (bf16_t*)(ws + 24 * MB);
  bf16_t* vt_ws = (bf16_t*)(ws + 32 * MB);
  bf16_t* at_ws = (bf16_t*)(ws + 40 * MB);

  hipLaunchKernelGGL(cast_all_k, dim3(8192), dim3(256), 0, stream,
                     x, wq, wk, wv, wo, xb, wqb, wkb, wvb, wob);

  hipLaunchKernelGGL(gemm_bt_k, dim3(8, 32, 3), dim3(256), 0, stream,
                     xb, wqb, wkb, wvb, q_ws, k_ws, vt_ws,
                     (float*)nullptr, (const float*)nullptr, 0);

  hipLaunchKernelGGL(attn_fused_k, dim3(32, 32), dim3(256), 0, stream,
                     q_ws, k_ws, vt_ws, at_ws);

  hipLaunchKernelGGL(gemm_bt_k, dim3(8, 32, 1), dim3(256), 0, stream,
                     at_ws, wob, wob, wob,
                     (bf16_t*)nullptr, (bf16_t*)nullptr, (bf16_t*)nullptr,
                     out, bo, 3);
}

// Round 4
// 331.781 us; speedup vs baseline: 1.4834x; 1.4834x over previous
//
#include <hip/hip_runtime.h>
#include <hip/hip_bf16.h>

#define B_    2
#define NSEQ  2048
#define FDIM  1024
#define NH    16
#define HD    64
#define MTOT  (B_*NSEQ)   // 4096

typedef __bf16 bf16_t;
typedef __bf16 bf16x4 __attribute__((ext_vector_type(4)));
typedef __bf16 bf16x8 __attribute__((ext_vector_type(8)));
typedef float  f32x4  __attribute__((ext_vector_type(4)));

#define AS1 __attribute__((address_space(1)))
#define AS3 __attribute__((address_space(3)))

__device__ __forceinline__ void gld_lds16(const bf16_t* g, bf16_t* l) {
  __builtin_amdgcn_global_load_lds((const AS1 void*)g, (AS3 void*)l, 16, 0, 0);
}

// K=16 bf16 MFMA for PV (P^T C-layout reg r == B-operand k-index j).
// All device-builtin probing must live inside __HIP_DEVICE_COMPILE__ —
// the host pass has none of these builtins.
__device__ __forceinline__ f32x4 mfma_pv(bf16x4 a, bf16x4 b, f32x4 c) {
#if defined(__HIP_DEVICE_COMPILE__)
#if __has_builtin(__builtin_amdgcn_mfma_f32_16x16x16bf16_1k)
  typedef short s4 __attribute__((ext_vector_type(4)));
  return __builtin_amdgcn_mfma_f32_16x16x16bf16_1k(
      __builtin_bit_cast(s4, a), __builtin_bit_cast(s4, b), c, 0, 0, 0);
#else
  asm("v_mfma_f32_16x16x16_bf16 %0, %1, %2, %0" : "+v"(c) : "v"(a), "v"(b));
  return c;
#endif
#else
  (void)a; (void)b;
  return c;  // host pass: never executed
#endif
}

// ---------------------------------------------------------------------------
// Kernel 1: fp32 -> bf16 casts for x, Wq, Wk, Wv, Wo
// ---------------------------------------------------------------------------
extern "C" __global__ __launch_bounds__(256) void cast_all_k(
    const float* __restrict__ x,  const float* __restrict__ wq,
    const float* __restrict__ wk, const float* __restrict__ wv,
    const float* __restrict__ wo,
    bf16_t* __restrict__ xb,  bf16_t* __restrict__ wqb,
    bf16_t* __restrict__ wkb, bf16_t* __restrict__ wvb,
    bf16_t* __restrict__ wob)
{
  long t = (long)blockIdx.x * blockDim.x + threadIdx.x;
  long i = t * 4;
  const float* src; bf16_t* dst; long off;
  if      (i < 4194304L) { src = x;  dst = xb;  off = i; }
  else if (i < 5242880L) { src = wq; dst = wqb; off = i - 4194304L; }
  else if (i < 6291456L) { src = wk; dst = wkb; off = i - 5242880L; }
  else if (i < 7340032L) { src = wv; dst = wvb; off = i - 6291456L; }
  else                   { src = wo; dst = wob; off = i - 7340032L; }
  float4 v = *(const float4*)(src + off);
  bf16x4 o = { (bf16_t)v.x, (bf16_t)v.y, (bf16_t)v.z, (bf16_t)v.w };
  *(bf16x4*)(dst + off) = o;
}

// ---------------------------------------------------------------------------
// Kernel 2/4: bf16 GEMM out[m][n] = sum_k A[m][k]*W[n][k]
// mode 0: write Q (pre-scaled by 2^-3, exact) [b][h][tok][d]
// mode 1: write K [b][h][tok][d]
// mode 2: write V transposed [b][h][d][tok]
// mode 3: write fp32 out [m][n] + bias[n]
// ---------------------------------------------------------------------------
extern "C" __global__ __launch_bounds__(256) void gemm_bt_k(
    const bf16_t* __restrict__ A,
    const bf16_t* __restrict__ Bq, const bf16_t* __restrict__ Bk,
    const bf16_t* __restrict__ Bv,
    bf16_t* __restrict__ oq, bf16_t* __restrict__ okk,
    bf16_t* __restrict__ ovt, float* __restrict__ oo,
    const float* __restrict__ bias, int mode_base)
{
  __shared__ __align__(16) bf16_t As[128*32];
  __shared__ __align__(16) bf16_t Bs[128*32];
  const int K = FDIM;
  int mode = mode_base + blockIdx.z;
  const bf16_t* Bw = (mode == 0) ? Bq : (mode == 1) ? Bk : (mode == 2) ? Bv : Bq;
  int m0 = blockIdx.y * 128, n0 = blockIdx.x * 128;
  int tid = threadIdx.x, lane = tid & 63, wave = tid >> 6;
  int g = lane >> 4, c = lane & 15;
  int wm = (wave >> 1) * 64, wn = (wave & 1) * 64;
  f32x4 acc[4][4];
  for (int i = 0; i < 4; ++i)
    for (int j = 0; j < 4; ++j)
      acc[i][j] = (f32x4){0.f, 0.f, 0.f, 0.f};

  int srow = lane >> 2;
  int scol = (lane & 3) * 8;

  for (int kt = 0; kt < K / 32; ++kt) {
    int kk = kt * 32;
    for (int cc = 0; cc < 2; ++cc) {
      int chunk = wave * 2 + cc;
      const bf16_t* ag = A  + (long)(m0 + chunk*16 + srow) * K + kk + scol;
      const bf16_t* bg = Bw + (long)(n0 + chunk*16 + srow) * K + kk + scol;
      gld_lds16(ag, As + chunk * 512);
      gld_lds16(bg, Bs + chunk * 512);
    }
    __syncthreads();
    bf16x8 af[4], bfr[4];
    for (int t = 0; t < 4; ++t) {
      af[t]  = *(const bf16x8*)(As + (wm + t*16 + c) * 32 + g * 8);
      bfr[t] = *(const bf16x8*)(Bs + (wn + t*16 + c) * 32 + g * 8);
    }
    for (int mt = 0; mt < 4; ++mt)
      for (int nt = 0; nt < 4; ++nt)
        acc[mt][nt] = __builtin_amdgcn_mfma_f32_16x16x32_bf16(
            af[mt], bfr[nt], acc[mt][nt], 0, 0, 0);
    __syncthreads();
  }

  if (mode < 2) {
    bf16_t* dst = (mode == 0) ? oq : okk;
    float sc = (mode == 0) ? 0.125f : 1.0f;   // fold softmax scale into Q (2^-3, exact)
    for (int mt = 0; mt < 4; ++mt)
      for (int nt = 0; nt < 4; ++nt) {
        int n = n0 + wn + nt*16 + c;
        int h = n >> 6, d = n & 63;
        for (int r = 0; r < 4; ++r) {
          int m = m0 + wm + mt*16 + g*4 + r;
          int b = m >> 11, tok = m & 2047;
          dst[((long)(b*NH + h) * NSEQ + tok) * HD + d] = (bf16_t)(acc[mt][nt][r] * sc);
        }
      }
  } else if (mode == 2) {
    for (int mt = 0; mt < 4; ++mt)
      for (int nt = 0; nt < 4; ++nt) {
        int n = n0 + wn + nt*16 + c;
        int h = n >> 6, d = n & 63;
        int m = m0 + wm + mt*16 + g*4;
        int b = m >> 11, tok = m & 2047;
        bf16x4 pk = { (bf16_t)acc[mt][nt][0], (bf16_t)acc[mt][nt][1],
                      (bf16_t)acc[mt][nt][2], (bf16_t)acc[mt][nt][3] };
        *(bf16x4*)(ovt + ((long)(b*NH + h) * HD + d) * NSEQ + tok) = pk;
      }
  } else {
    for (int mt = 0; mt < 4; ++mt)
      for (int nt = 0; nt < 4; ++nt) {
        int n = n0 + wn + nt*16 + c;
        float bv = bias[n];
        for (int r = 0; r < 4; ++r) {
          int m = m0 + wm + mt*16 + g*4 + r;
          oo[(long)m * FDIM + n] = acc[mt][nt][r] + bv;
        }
      }
  }
}

// ---------------------------------------------------------------------------
// Kernel 3: flash attention, transposed-S formulation, 32 q-cols/wave,
// software-pipelined: K-frags register double-buffered (loaded one tile
// ahead), V-frags issued before softmax and consumed after (exp/shfl chain
// hides their L2 latency). No barriers, no LDS in the main loop.
// ---------------------------------------------------------------------------
extern "C" __global__ __launch_bounds__(256) void attn_fused_k(
    const bf16_t* __restrict__ q, const bf16_t* __restrict__ k,
    const bf16_t* __restrict__ vt, bf16_t* __restrict__ attn)
{
  __shared__ __align__(16) bf16_t Ol[4 * 32 * 80];   // 20 KB (epilogue only)
  int bh = blockIdx.y;
  int tid = threadIdx.x, lane = tid & 63, wave = tid >> 6;
  int g = lane >> 4, c = lane & 15;
  int qw = blockIdx.x * 128 + wave * 32;
  const bf16_t* Q  = q  + (long)bh * NSEQ * HD;
  const bf16_t* Kp = k  + (long)bh * NSEQ * HD;
  const bf16_t* Vt = vt + (long)bh * HD * NSEQ;

  // Q^T B-frags for 2 q-sets (16 cols each): set s col = qw + s*16 + c
  bf16x8 bQ[2][2];
#pragma unroll
  for (int s = 0; s < 2; ++s)
#pragma unroll
    for (int hh = 0; hh < 2; ++hh)
      bQ[s][hh] = *(const bf16x8*)(Q + (long)(qw + s*16 + c) * HD + hh*32 + g*8);

  f32x4 acc[2][4];
#pragma unroll
  for (int s = 0; s < 2; ++s)
#pragma unroll
    for (int dt = 0; dt < 4; ++dt) acc[s][dt] = (f32x4){0.f, 0.f, 0.f, 0.f};
  float mrun[2] = {-1e30f, -1e30f}, lrun[2] = {0.f, 0.f};

  // K-frag double buffer; preload tile 0
  bf16x8 kf[2][4][2];
#pragma unroll
  for (int mt = 0; mt < 4; ++mt) {
    const bf16_t* kp = Kp + (long)(mt*16 + c) * HD + g*8;
    kf[0][mt][0] = *(const bf16x8*)(kp);
    kf[0][mt][1] = *(const bf16x8*)(kp + 32);
  }

#pragma unroll 2
  for (int kt = 0; kt < NSEQ / 64; ++kt) {
    int k0 = kt * 64;
    int cur = kt & 1, nxt = cur ^ 1;

    // 1) issue V loads for THIS tile (consumed after softmax)
    bf16x4 vf[4][4];
#pragma unroll
    for (int mt = 0; mt < 4; ++mt)
#pragma unroll
      for (int dt = 0; dt < 4; ++dt)
        vf[mt][dt] = *(const bf16x4*)(Vt + (long)(dt*16 + c) * NSEQ
                                      + k0 + mt*16 + g*4);

    // 2) S^T = K · Q^T for both q-sets, from current K buffer
    f32x4 St[2][4];
#pragma unroll
    for (int mt = 0; mt < 4; ++mt)
#pragma unroll
      for (int s = 0; s < 2; ++s) {
        f32x4 z = (f32x4){0.f, 0.f, 0.f, 0.f};
        z = __builtin_amdgcn_mfma_f32_16x16x32_bf16(kf[cur][mt][0], bQ[s][0], z, 0, 0, 0);
        z = __builtin_amdgcn_mfma_f32_16x16x32_bf16(kf[cur][mt][1], bQ[s][1], z, 0, 0, 0);
        St[s][mt] = z;
      }

    // 3) issue K loads for NEXT tile into the other buffer
    if (kt + 1 < NSEQ / 64) {
#pragma unroll
      for (int mt = 0; mt < 4; ++mt) {
        const bf16_t* kp = Kp + (long)(k0 + 64 + mt*16 + c) * HD + g*8;
        kf[nxt][mt][0] = *(const bf16x8*)(kp);
        kf[nxt][mt][1] = *(const bf16x8*)(kp + 32);
      }
    }

    // 4) online softmax per q-set (reduction axis = regs + 2 shfls)
    bf16x4 bP[2][4];
#pragma unroll
    for (int s = 0; s < 2; ++s) {
      f32x4 vm0 = (f32x4){fmaxf(St[s][0][0], St[s][1][0]), fmaxf(St[s][0][1], St[s][1][1]),
                          fmaxf(St[s][0][2], St[s][1][2]), fmaxf(St[s][0][3], St[s][1][3])};
      f32x4 vm1 = (f32x4){fmaxf(St[s][2][0], St[s][3][0]), fmaxf(St[s][2][1], St[s][3][1]),
                          fmaxf(St[s][2][2], St[s][3][2]), fmaxf(St[s][2][3], St[s][3][3])};
      float pm = fmaxf(fmaxf(fmaxf(vm0[0], vm1[0]), fmaxf(vm0[1], vm1[1])),
                       fmaxf(fmaxf(vm0[2], vm1[2]), fmaxf(vm0[3], vm1[3])));
      pm = fmaxf(pm, __shfl_xor(pm, 16));
      pm = fmaxf(pm, __shfl_xor(pm, 32));
      float mnew = fmaxf(mrun[s], pm);
      float alpha = __expf(mrun[s] - mnew);
      f32x4 vsum = (f32x4){0.f, 0.f, 0.f, 0.f};
#pragma unroll
      for (int mt = 0; mt < 4; ++mt)
#pragma unroll
        for (int r = 0; r < 4; ++r) {
          float p = __expf(St[s][mt][r] - mnew);
          St[s][mt][r] = p;
          vsum[r] += p;
        }
      float ps = (vsum[0] + vsum[1]) + (vsum[2] + vsum[3]);
      ps += __shfl_xor(ps, 16);
      ps += __shfl_xor(ps, 32);
      lrun[s] = lrun[s] * alpha + ps;
      mrun[s] = mnew;
#pragma unroll
      for (int dt = 0; dt < 4; ++dt) acc[s][dt] *= alpha;
#pragma unroll
      for (int mt = 0; mt < 4; ++mt)
        bP[s][mt] = (bf16x4){(bf16_t)St[s][mt][0], (bf16_t)St[s][mt][1],
                             (bf16_t)St[s][mt][2], (bf16_t)St[s][mt][3]};
    }

    // 5) O^T += V^T · P^T ; each vf reused for both q-sets
#pragma unroll
    for (int mt = 0; mt < 4; ++mt)
#pragma unroll
      for (int s = 0; s < 2; ++s)
#pragma unroll
        for (int dt = 0; dt < 4; ++dt)
          acc[s][dt] = mfma_pv(vf[mt][dt], bP[s][mt], acc[s][dt]);
  }

  // epilogue: O^T -> LDS -> coalesced O stores (32 rows/wave)
  bf16_t* Ow = Ol + wave * (32 * 80);
#pragma unroll
  for (int s = 0; s < 2; ++s) {
    float invl = 1.f / lrun[s];
#pragma unroll
    for (int dt = 0; dt < 4; ++dt)
#pragma unroll
      for (int r = 0; r < 4; ++r)
        Ow[(s*16 + c) * 80 + dt*16 + g*4 + r] = (bf16_t)(acc[s][dt][r] * invl);
  }
  __syncthreads();
  int b = bh >> 4, h = bh & 15;
  int qr = lane >> 1, dseg = (lane & 1) * 32;   // 2 lanes per q-row, 32 elems each
  bf16_t* dst = attn + ((long)(b * NSEQ + qw + qr)) * FDIM + h * HD + dseg;
#pragma unroll
  for (int u = 0; u < 4; ++u)
    *(bf16x8*)(dst + u*8) = *(const bf16x8*)(Ow + qr * 80 + dseg + u*8);
}

// ---------------------------------------------------------------------------
extern "C" void kernel_launch(void* const* d_in, const int* in_sizes, int n_in,
                              void* d_out, int out_size, void* d_ws, size_t ws_size,
                              hipStream_t stream)
{
  const float* x  = (const float*)d_in[0];
  const float* wq = (const float*)d_in[1];
  const float* wk = (const float*)d_in[2];
  const float* wv = (const float*)d_in[3];
  const float* wo = (const float*)d_in[4];
  const float* bo = (const float*)d_in[5];
  float* out = (float*)d_out;
  char* ws = (char*)d_ws;

  const size_t MB = 1024 * 1024;
  bf16_t* xb    = (bf16_t*)(ws);
  bf16_t* wqb   = (bf16_t*)(ws + 8  * MB);
  bf16_t* wkb   = (bf16_t*)(ws + 10 * MB);
  bf16_t* wvb   = (bf16_t*)(ws + 12 * MB);
  bf16_t* wob   = (bf16_t*)(ws + 14 * MB);
  bf16_t* q_ws  = (bf16_t*)(ws + 16 * MB);
  bf16_t* k_ws  = (bf16_t*)(ws + 24 * MB);
  bf16_t* vt_ws = (bf16_t*)(ws + 32 * MB);
  bf16_t* at_ws = (bf16_t*)(ws + 40 * MB);

  hipLaunchKernelGGL(cast_all_k, dim3(8192), dim3(256), 0, stream,
                     x, wq, wk, wv, wo, xb, wqb, wkb, wvb, wob);

  hipLaunchKernelGGL(gemm_bt_k, dim3(8, 32, 3), dim3(256), 0, stream,
                     xb, wqb, wkb, wvb, q_ws, k_ws, vt_ws,
                     (float*)nullptr, (const float*)nullptr, 0);

  hipLaunchKernelGGL(attn_fused_k, dim3(16, 32), dim3(256), 0, stream,
                     q_ws, k_ws, vt_ws, at_ws);

  hipLaunchKernelGGL(gemm_bt_k, dim3(8, 32, 1), dim3(256), 0, stream,
                     at_ws, wob, wob, wob,
                     (bf16_t*)nullptr, (bf16_t*)nullptr, (bf16_t*)nullptr,
                     out, bo, 3);
}